// Round 13
// baseline (176.787 us; speedup 1.0000x reference)
//
#include <hip/hip_runtime.h>

typedef _Float16 f16;
typedef f16 f16x8 __attribute__((ext_vector_type(8)));
typedef float f32x4 __attribute__((ext_vector_type(4)));
typedef float f32x16 __attribute__((ext_vector_type(16)));

#define BATCH   32768
#define NF      162
#define ACCH    1024
#define NKS2    12        // 32x32x16 K-steps per 192
#define NB      8
#define DIVQ    20
#define TM      32        // rows per tile
#define NT      256       // k_main threads (4 waves)
#define NCH     128       // chunk width
#define NCHUNK  8
#define MAXTILE (BATCH/TM + NB)   // 1032
#define REG     8192      // per-bucket order region

#define PBIN    128       // binning/pack blocks (256 rows each, thread-per-row)
#define PROWS   256
#define PGRID   512       // 128 bin + 384 conversion blocks

// workspace layout (bytes)
#define WS_WACC16   0
#define WS_W116     (ACCH*192*2)                   // 393216
#define WS_PBITS    (WS_W116 + 256*2048*2)         // 2490368 (BATCH rows x 16 u32)
#define WS_PSQ      (WS_PBITS + BATCH*64)          // 4587520
#define WS_ORDER    (WS_PSQ + BATCH*4)             // 4718592
#define WS_CNT      (WS_ORDER + NB*REG*4)          // 4980736

// k_main dynamic LDS: Xb[2][32][128] f16 = 16384 (h1s/h2s alias)
#define LDS_BYTES   16384

// expand 8 bits -> f16x8 of 0.0/1.0
__device__ __forceinline__ f16x8 expand8(unsigned b) {
    union { unsigned u[4]; f16x8 h; } r;
    r.u[0] = ((b & 1u)   ? 0x3C00u : 0u) | ((b & 2u)   ? 0x3C000000u : 0u);
    r.u[1] = ((b & 4u)   ? 0x3C00u : 0u) | ((b & 8u)   ? 0x3C000000u : 0u);
    r.u[2] = ((b & 16u)  ? 0x3C00u : 0u) | ((b & 32u)  ? 0x3C000000u : 0u);
    r.u[3] = ((b & 64u)  ? 0x3C00u : 0u) | ((b & 128u) ? 0x3C000000u : 0u);
    return r.h;
}

// ---------------- dispatch 1: pack bits + psqt + binning + weight conv ----------------
__global__ __launch_bounds__(256) void k_prep(const float* __restrict__ stm,
                                              const float* __restrict__ nstm,
                                              const float* __restrict__ Wacc,
                                              const float* __restrict__ W1,
                                              int* __restrict__ cnt,
                                              int* __restrict__ order,
                                              unsigned* __restrict__ pbits,
                                              float* __restrict__ psq_g,
                                              f16* __restrict__ waccF,
                                              f16* __restrict__ w1F)
{
    int tid = threadIdx.x, bid = blockIdx.x;
    if (bid < PBIN) {
        __shared__ int bkt_l[PROWS];
        __shared__ int hist[NB], gb[NB];
        if (tid < NB) hist[tid] = 0;
        __syncthreads();
        int row = bid * PROWS + tid;             // thread-per-row
        const float* rs = stm  + (long)row * NF;
        const float* rn = nstm + (long)row * NF;
        const float* pw = Wacc + (long)ACCH * NF;   // psqt weight row
        unsigned bw_s[6] = {0,0,0,0,0,0}, bw_n[6] = {0,0,0,0,0,0};
        float ds = 0.f, dn = 0.f;
        #pragma unroll
        for (int q = 0; q < 40; q++) {
            float4 vs = *(const float4*)(rs + q * 4);
            float4 vn = *(const float4*)(rn + q * 4);
            float4 pv = *(const float4*)(pw + q * 4);
            const int w = (q * 4) >> 5, sh = (q * 4) & 31;
            bw_s[w] |= (((vs.x != 0.f) ? 1u : 0u)      | ((vs.y != 0.f) ? 2u : 0u)
                      | ((vs.z != 0.f) ? 4u : 0u)      | ((vs.w != 0.f) ? 8u : 0u)) << sh;
            bw_n[w] |= (((vn.x != 0.f) ? 1u : 0u)      | ((vn.y != 0.f) ? 2u : 0u)
                      | ((vn.z != 0.f) ? 4u : 0u)      | ((vn.w != 0.f) ? 8u : 0u)) << sh;
            ds += vs.x * pv.x + vs.y * pv.y + vs.z * pv.z + vs.w * pv.w;
            dn += vn.x * pv.x + vn.y * pv.y + vn.z * pv.z + vn.w * pv.w;
        }
        {   // tail k = 160,161 -> word 5 bits 0,1
            float2 ts = *(const float2*)(rs + 160);
            float2 tn = *(const float2*)(rn + 160);
            float2 tp = *(const float2*)(pw + 160);
            bw_s[5] |= ((ts.x != 0.f) ? 1u : 0u) | ((ts.y != 0.f) ? 2u : 0u);
            bw_n[5] |= ((tn.x != 0.f) ? 1u : 0u) | ((tn.y != 0.f) ? 2u : 0u);
            ds += ts.x * tp.x + ts.y * tp.y;
            dn += tn.x * tp.x + tn.y * tp.y;
        }
        uint4* pb = (uint4*)(pbits + (long)row * 16);
        pb[0] = make_uint4(bw_s[0], bw_s[1], bw_s[2], bw_s[3]);
        pb[1] = make_uint4(bw_s[4], bw_s[5], 0u, 0u);
        pb[2] = make_uint4(bw_n[0], bw_n[1], bw_n[2], bw_n[3]);
        pb[3] = make_uint4(bw_n[4], bw_n[5], 0u, 0u);
        psq_g[row] = 0.5f * (ds - dn);
        int pc = __popc(bw_s[0]) + __popc(bw_s[1]) + __popc(bw_s[2])
               + __popc(bw_s[3]) + __popc(bw_s[4]) + __popc(bw_s[5]);
        int b = pc / DIVQ; if (b > NB - 1) b = NB - 1;
        bkt_l[tid] = b;
        atomicAdd(&hist[b], 1);
        __syncthreads();
        if (tid < NB) gb[tid] = atomicAdd(&cnt[tid], hist[tid]);
        __syncthreads();
        if (tid < NB) hist[tid] = gb[tid];
        __syncthreads();
        int b2 = bkt_l[tid];
        int pos = atomicAdd(&hist[b2], 1);
        if (pos < REG) order[b2 * REG + pos] = row;
    } else {
        int t0 = (bid - PBIN) * 256 + tid;
        const int STRIDE = (PGRID - PBIN) * 256;   // 98304
        // waccF (32x32x16 B-frag): idx = (((c*12+ks)*2+kh)*128+n)*8+e, k=ks*16+kh*8+e
        for (int t = t0; t < ACCH * 192; t += STRIDE) {
            int e = t & 7, f = t >> 3;
            int n = f & 127, g = f >> 7;
            int kh = g & 1, h = g >> 1;
            int ks = h % NKS2, c = h / NKS2;
            int k = ks * 16 + kh * 8 + e;
            waccF[t] = (f16)((k < NF) ? Wacc[(c * 128 + n) * NF + k] : 0.f);
        }
        // w1F (16x16x32 B-frag): output-linear
        for (int f = t0; f < 256 * 2048 / 8; f += STRIDE) {
            int n = f & 31, g = f >> 5;
            int l4b = g & 3, ks = (g >> 2) & 3, c = (g >> 4) & 7;
            int s = (g >> 7) & 1, bkt = g >> 8;
            int k0 = s * 1024 + c * 128 + ks * 32 + l4b * 8;
            const float* src = W1 + (long)(bkt * 32 + n) * 2048 + k0;
            float4 va = *(const float4*)(src);
            float4 vb = *(const float4*)(src + 4);
            f16x8 h;
            h[0]=(f16)va.x; h[1]=(f16)va.y; h[2]=(f16)va.z; h[3]=(f16)va.w;
            h[4]=(f16)vb.x; h[5]=(f16)vb.y; h[6]=(f16)vb.z; h[7]=(f16)vb.w;
            *(f16x8*)(w1F + (long)f * 8) = h;
        }
    }
}

// ---------------- dispatch 2: main fused NNUE (bit features, shared B-frags) ----------------
__global__ __launch_bounds__(NT, 2) void k_main(
    const float* __restrict__ bacc, const float* __restrict__ b1,
    const float* __restrict__ W2, const float* __restrict__ b2,
    const float* __restrict__ W3, const float* __restrict__ b3,
    const f16* __restrict__ waccF, const f16* __restrict__ w1F,
    const unsigned* __restrict__ pbits, const float* __restrict__ psq_g,
    const int* __restrict__ cnt, const int* __restrict__ order,
    float* __restrict__ out)
{
    // ---- inline tile map from the 8 counters ----
    int t = blockIdx.x;
    int bkt = -1, tile = 0, cb = 0, ta = 0;
    #pragma unroll
    for (int b = 0; b < NB; b++) {
        int cbv = cnt[b];
        int nb = (cbv + TM - 1) / TM;
        if (bkt < 0 && t < ta + nb) { bkt = b; tile = t - ta; cb = cbv; }
        ta += nb;
    }
    if (bkt < 0) return;
    int rowbase = bkt * REG + tile * TM;
    int nrows = cb - tile * TM; if (nrows > TM) nrows = TM;

    extern __shared__ __align__(16) char lds_raw[];
    f16* Xb  = (f16*)lds_raw;                           // [2][32][128] swizzled (both sides)
    f16* h1s = (f16*)lds_raw;                           // [32][40] alias
    f16* h2s = (f16*)(lds_raw + TM * 40 * 2);           // [32][40] alias

    int tid = threadIdx.x;
    int wv = tid >> 6, ln = tid & 63;
    int l15 = ln & 15, l4 = ln >> 4, l31 = ln & 31, kh = ln >> 5;
    int mt = wv >> 1, nh = wv & 1;
    int colc = wv * 32 + l31;                 // phase1 col within chunk
    int shb = kh << 3;                        // bit shift base for this lane's k-half

    int rowclamp = (l31 < nrows) ? l31 : (nrows - 1);
    int rowidx = order[rowbase + rowclamp];

    // ---- packed feature bits: 6 u32 per side ----
    const unsigned* pb = pbits + (long)rowidx * 16;
    uint4 sa = *(const uint4*)(pb);
    uint2 sbv = *(const uint2*)(pb + 4);
    uint4 na = *(const uint4*)(pb + 8);
    uint2 nbv = *(const uint2*)(pb + 12);
    unsigned bs[6] = {sa.x, sa.y, sa.z, sa.w, sbv.x, sbv.y};
    unsigned bn[6] = {na.x, na.y, na.z, na.w, nbv.x, nbv.y};

    float bb1 = b1[bkt * 32 + nh * 16 + l15];
    f32x4 h1acc; h1acc[0] = h1acc[1] = h1acc[2] = h1acc[3] = bb1;

    const f16x8* wfr  = (const f16x8*)waccF;
    const f16x8* w1fr = (const f16x8*)w1F;

    for (int c = 0; c < NCHUNK; c++) {
        // ---- phase 1: both sides, B-frag loaded ONCE per ks ----
        float bias = bacc[c * NCH + colc];
        f32x16 acc0, acc1;
        #pragma unroll
        for (int q = 0; q < 16; q++) { acc0[q] = bias; acc1[q] = bias; }
        const f16x8* wp = wfr + ((c * NKS2) * 2 + kh) * 128 + colc;
        #pragma unroll
        for (int ks = 0; ks < NKS2; ks++) {
            f16x8 bf = wp[ks * 256];
            unsigned sh = ((ks & 1) << 4) + shb;
            f16x8 a0 = expand8((bs[ks >> 1] >> sh) & 0xFFu);
            acc0 = __builtin_amdgcn_mfma_f32_32x32x16_f16(a0, bf, acc0, 0, 0, 0);
            f16x8 a1 = expand8((bn[ks >> 1] >> sh) & 0xFFu);
            acc1 = __builtin_amdgcn_mfma_f32_32x32x16_f16(a1, bf, acc1, 0, 0, 0);
        }
        __syncthreads();   // phase2 readers of previous chunk done
        // ---- epilogue: clip^2 both sides -> Xb[side] ----
        #pragma unroll
        for (int reg = 0; reg < 16; reg++) {
            int rr = 4 * kh + (reg & 3) + 8 * (reg >> 2);
            int sw = (((colc >> 3) ^ (rr & 7)) << 3) | (colc & 7);
            float v0 = fminf(fmaxf(acc0[reg], 0.f), 1.f);
            Xb[rr * NCH + sw] = (f16)(v0 * v0);
            float v1 = fminf(fmaxf(acc1[reg], 0.f), 1.f);
            Xb[TM * NCH + rr * NCH + sw] = (f16)(v1 * v1);
        }
        __syncthreads();   // Xb ready
        // ---- phase 2: h1 += act_stm @ W1[s=0,c] + act_nstm @ W1[s=1,c] ----
        #pragma unroll
        for (int s = 0; s < 2; s++) {
            const f16x8* w1p = w1fr + ((bkt * 2 + s) * 8 + c) * 512;
            const f16* xb = Xb + s * TM * NCH;
            #pragma unroll
            for (int ks = 0; ks < 4; ks++) {
                int s0 = ks * 4 + l4;
                int row = mt * 16 + l15;
                f16x8 a = *(const f16x8*)(xb + row * NCH + ((s0 ^ (row & 7)) << 3));
                f16x8 b = w1p[s0 * 32 + nh * 16 + l15];
                h1acc = __builtin_amdgcn_mfma_f32_16x16x32_f16(a, b, h1acc, 0, 0, 0);
            }
        }
    }
    __syncthreads();   // all phase2 reads done before h1s/h2s overwrite

    // ---- h1 finalize ----
    #pragma unroll
    for (int jr = 0; jr < 4; jr++) {
        int row = mt * 16 + l4 * 4 + jr;
        int col = nh * 16 + l15;
        float v = fminf(fmaxf(h1acc[jr], 0.f), 1.f);
        h1s[row * 40 + col] = (f16)v;
    }
    __syncthreads();

    // ---- layer 3 ----
    {
        int nn = nh * 16 + l15;
        const float* w2r = W2 + (bkt * 32 + nn) * 32;
        float4 wa = *(const float4*)(w2r + l4 * 8);
        float4 wb = *(const float4*)(w2r + l4 * 8 + 4);
        f16x8 bfr;
        bfr[0]=(f16)wa.x; bfr[1]=(f16)wa.y; bfr[2]=(f16)wa.z; bfr[3]=(f16)wa.w;
        bfr[4]=(f16)wb.x; bfr[5]=(f16)wb.y; bfr[6]=(f16)wb.z; bfr[7]=(f16)wb.w;
        int row = mt * 16 + l15;
        f16x8 a = *(const f16x8*)(h1s + row * 40 + l4 * 8);
        float bb2 = b2[bkt * 32 + nn];
        f32x4 acc2; acc2[0] = acc2[1] = acc2[2] = acc2[3] = bb2;
        acc2 = __builtin_amdgcn_mfma_f32_16x16x32_f16(a, bfr, acc2, 0, 0, 0);
        #pragma unroll
        for (int jr = 0; jr < 4; jr++) {
            int r2 = mt * 16 + l4 * 4 + jr;
            float v = fminf(fmaxf(acc2[jr], 0.f), 1.f);
            h2s[r2 * 40 + nn] = (f16)v;
        }
    }
    __syncthreads();

    // ---- layer 4 + psqt (precomputed) ----
    if (tid < nrows) {
        const float* w3r = W3 + bkt * 32;
        float o = b3[bkt] + psq_g[rowidx];
        #pragma unroll 8
        for (int n = 0; n < 32; n++) o += (float)h2s[tid * 40 + n] * w3r[n];
        out[rowidx] = o;
    }
}

// ---------------- launcher ----------------
extern "C" void kernel_launch(void* const* d_in, const int* in_sizes, int n_in,
                              void* d_out, int out_size, void* d_ws, size_t ws_size,
                              hipStream_t stream)
{
    (void)in_sizes; (void)n_in; (void)out_size; (void)ws_size;
    const float* stm  = (const float*)d_in[0];
    const float* nstm = (const float*)d_in[1];
    const float* Wacc = (const float*)d_in[2];
    const float* bacc = (const float*)d_in[3];
    const float* W1   = (const float*)d_in[4];
    const float* b1   = (const float*)d_in[5];
    const float* W2   = (const float*)d_in[6];
    const float* b2   = (const float*)d_in[7];
    const float* W3   = (const float*)d_in[8];
    const float* b3   = (const float*)d_in[9];
    float* out = (float*)d_out;

    char* ws = (char*)d_ws;
    f16* waccF   = (f16*)(ws + WS_WACC16);
    f16* w1F     = (f16*)(ws + WS_W116);
    unsigned* pbits = (unsigned*)(ws + WS_PBITS);
    float* psq_g = (float*)(ws + WS_PSQ);
    int* order   = (int*)(ws + WS_ORDER);
    int* cnt     = (int*)(ws + WS_CNT);

    hipMemsetAsync(cnt, 0, NB * sizeof(int), stream);
    hipLaunchKernelGGL(k_prep, dim3(PGRID), dim3(256), 0, stream,
                       stm, nstm, Wacc, W1, cnt, order, pbits, psq_g, waccF, w1F);

    hipFuncSetAttribute(reinterpret_cast<const void*>(k_main),
                        hipFuncAttributeMaxDynamicSharedMemorySize, LDS_BYTES);
    hipLaunchKernelGGL(k_main, dim3(MAXTILE), dim3(NT), LDS_BYTES, stream,
                       bacc, b1, W2, b2, W3, b3,
                       waccF, w1F, pbits, psq_g, cnt, order, out);
}